// Round 11
// baseline (604.448 us; speedup 1.0000x reference)
//
#include <hip/hip_runtime.h>
#include <stdint.h>

// Problem constants (from reference setup_inputs)
constexpr int N_NODES = 50000;
constexpr int E_EDGES = 800000;
constexpr int E_PAIR  = 200000;   // pos edges; neg edges same count
constexpr int C_IN    = 256;
constexpr int C_HID   = 128;
constexpr int C_OUT   = 64;
constexpr int SLOT    = 64;       // fixed CSR slot; max degree ~45 (Poisson 16)

// Two-phase binned build (196 buckets of 256 nodes)
constexpr int NBUCK = 196;        // dst >> 8  (196*256 = 50176 >= 50000)
constexpr int BCAP  = 4608;       // per-bucket capacity (mean 4082, ~8 sigma)
constexpr int CHUNK = 4096;       // edges per binA block (84B runs -> coalesced)
constexpr int PREPB = 32;         // prep blocks merged into binA dispatch
constexpr int BINAB = (E_EDGES + CHUNK - 1) / CHUNK;   // 196
constexpr int GEMM1_BLOCKS = (N_NODES + 63) / 64;      // 782

// Fused tail (normal launch + software global barrier).
// 1024 blocks = 4/CU x 256 CU — guaranteed co-resident: launch_bounds(256,4)
// caps VGPR at 128 (kernel uses 64), LDS 4KB, 16 waves/CU <= 32.
constexpr int TAIL_BLOCKS = 1024;
constexpr int GG_GROUPS   = N_NODES / 16;              // 3125
constexpr int G2_GROUPS   = (N_NODES + 31) / 32;       // 1563
constexpr int LG_GROUPS   = (E_PAIR * 8 + 255) / 256;  // 6250

typedef __attribute__((ext_vector_type(8))) _Float16 f16x8;  // 8 f16 (4 VGPRs)
typedef __attribute__((ext_vector_type(2))) _Float16 f16x2;
typedef __attribute__((ext_vector_type(4))) float f32x4;

__device__ inline uint16_t f2h_bits(float v) {             // RNE fp32->f16 bits
    union { _Float16 h; uint16_t u; } c; c.h = (_Float16)v;
    return c.u;
}
__device__ inline uint32_t pack2h(float a, float b) {
    return (uint32_t)f2h_bits(a) | ((uint32_t)f2h_bits(b) << 16);
}
// accumulate 8 f16 (uint4) into 8 fp32 — cvt+add / fma_mix path
__device__ inline void acc_h8(float* a, uint4 v) {
    union { uint4 u; _Float16 h[8]; } c; c.u = v;
#pragma unroll
    for (int i = 0; i < 8; ++i) a[i] += (float)c.h[i];
}
// accumulate 8 f16 scaled by s into 8 fp32 — targets v_fma_mix_f32
__device__ inline void acc_h8s(float* a, uint4 v, float s) {
    union { uint4 u; _Float16 h[8]; } c; c.u = v;
#pragma unroll
    for (int i = 0; i < 8; ++i) a[i] += (float)c.h[i] * s;
}
__device__ inline float dot_h8(uint4 a, uint4 b) {
    union { uint4 u; f16x2 h[4]; } ca, cb; ca.u = a; cb.u = b;
    float v = 0.f;
#pragma unroll
    for (int i = 0; i < 4; ++i) {
#if __has_builtin(__builtin_amdgcn_fdot2)
        v = __builtin_amdgcn_fdot2(ca.h[i], cb.h[i], v, false);
#else
        v += (float)ca.h[i][0] * (float)cb.h[i][0]
           + (float)ca.h[i][1] * (float)cb.h[i][1];
#endif
    }
    return v;
}

// Software grid barrier. R10 lesson: spinning with atomicAdd(cnt,0) (an RMW)
// serializes ~1000 blocks' polls on one line and clogs the atomic pipe for
// the still-working blocks (359us, VALUBusy 6%). Fix: arrive with ONE RMW,
// spin on an ATOMIC LOAD (read-only, LLC-served, no serialization) + heavy
// s_sleep backoff. Bounded spin: pathological failure = wrong result, not hang.
__device__ inline void global_barrier(int* cnt, int nblk) {
    __syncthreads();
    if (threadIdx.x == 0) {
        __threadfence();                      // release my prior writes
        __hip_atomic_fetch_add(cnt, 1, __ATOMIC_ACQ_REL, __HIP_MEMORY_SCOPE_AGENT);
        long guard = 0;
        while (__hip_atomic_load(cnt, __ATOMIC_ACQUIRE, __HIP_MEMORY_SCOPE_AGENT) < nblk
               && guard < (1L << 24)) {
            __builtin_amdgcn_s_sleep(32);     // ~0.85us per poll
            ++guard;
        }
        __threadfence();                      // acquire others' writes
    }
    __syncthreads();
}

// W swizzle index (MFMA B-frag order)
template<int N>
__device__ inline int wswz_idx(int k, int n) {
    int c = k >> 5, kq = (k >> 3) & 3, kk = k & 7, ct = n >> 4, nn = n & 15;
    return (((c * (N / 16) + ct) * 4 + kq) * 16 + nn) * 8 + kk;
}

// ---------------------------------------------------------------------------
// MERGED prep + binA (unchanged from R8)
// ---------------------------------------------------------------------------
__global__ __launch_bounds__(256) void prep_binA_kernel(
        const float* __restrict__ W1, const float* __restrict__ W2,
        uint16_t* __restrict__ s1, uint16_t* __restrict__ s2,
        const int* __restrict__ src, const int* __restrict__ dst,
        int* __restrict__ gcur, uint32_t* __restrict__ ebuf) {
    __shared__ int cnt[NBUCK], loc[NBUCK], lim[NBUCK], abase[NBUCK], wcur[NBUCK];
    __shared__ int tot;
    __shared__ uint32_t stag[CHUNK];            // 16 KB

    const int t = threadIdx.x;

    if (blockIdx.x < PREPB) {
        for (int id = blockIdx.x * 256 + t;
             id < C_IN * C_HID + C_HID * C_OUT; id += PREPB * 256) {
            if (id < C_IN * C_HID) {
                int idx = wswz_idx<C_HID>(id / C_HID, id & (C_HID - 1));
                s1[idx] = f2h_bits(W1[id]);
            } else {
                int id2 = id - C_IN * C_HID;
                int idx = wswz_idx<C_OUT>(id2 / C_OUT, id2 & (C_OUT - 1));
                s2[idx] = f2h_bits(W2[id2]);
            }
        }
        return;
    }

    const int e0 = (blockIdx.x - PREPB) * CHUNK;
    const int n  = min(CHUNK, E_EDGES - e0);

    for (int b = t; b < NBUCK; b += 256) cnt[b] = 0;
    if (t == 0) tot = 0;
    __syncthreads();

    uint32_t pk[CHUNK / 256];                   // 16 regs
    int ne = 0;
    for (int j = t; j < n; j += 256) {
        int d = dst[e0 + j], s = src[e0 + j];
        int b = d >> 8;
        pk[ne] = ((uint32_t)b << 24) | ((uint32_t)(d & 255) << 16) | (uint32_t)s;
        atomicAdd(&cnt[b], 1);
        ++ne;
    }
    __syncthreads();
    for (int b = t; b < NBUCK; b += 256)
        loc[b] = atomicAdd(&tot, cnt[b]);       // unordered contiguous packing
    __syncthreads();
    for (int b = t; b < NBUCK; b += 256) {
        int base = atomicAdd(&gcur[b], cnt[b]);
        int room = BCAP - base; if (room < 0) room = 0;
        lim[b]   = loc[b] + room;
        abase[b] = b * BCAP + base - loc[b];
        wcur[b]  = loc[b];
    }
    __syncthreads();
#pragma unroll
    for (int i = 0; i < CHUNK / 256; ++i) {
        if (i < ne) {
            int p = atomicAdd(&wcur[pk[i] >> 24], 1);
            stag[p] = pk[i];
        }
    }
    __syncthreads();
    for (int j = t; j < n; j += 256) {
        uint32_t v = stag[j];
        int b = v >> 24;
        if (j < lim[b]) ebuf[abase[b] + j] = v & 0x00ffffffu;
    }
}

// ---------------------------------------------------------------------------
// MERGED binB + gemm1 (unchanged from R8)
// ---------------------------------------------------------------------------
__global__ __launch_bounds__(256, 3) void build_gemm_kernel(
        const int* __restrict__ gcur, const uint32_t* __restrict__ ebuf,
        uint16_t* __restrict__ col2, int* __restrict__ degc,
        float* __restrict__ dinv,
        const float* __restrict__ A, const uint16_t* __restrict__ Bswz,
        uint16_t* __restrict__ out) {
    constexpr int K = C_IN, N = C_HID;
    constexpr int BM = 64, BK = 32;
    constexpr int CT   = N / 32;            // 4
    constexpr int NSUB = N / 16;            // 8
    constexpr int ABYTES = BM * BK * 2;     // 4096
    constexpr int BBYTES = NSUB * 1024;     // 8192
    __shared__ char sm[1024 + 256 * SLOT * 2];   // 33 KB

    const int t = threadIdx.x;

    if (blockIdx.x < NBUCK) {
        // ================= binB (LDS-staged col2) =================
        int* cur = (int*)sm;                        // 256 counters
        uint16_t* colL = (uint16_t*)(sm + 1024);    // 256 x 64 u16
        const int b = blockIdx.x;
        cur[t] = 0;
        __syncthreads();

        int cn = gcur[b]; if (cn > BCAP) cn = BCAP;
        const uint32_t* eb = ebuf + (size_t)b * BCAP;
        const int nbase = b << 8;

        int j = t;
        for (; j + 3 * 256 < cn; j += 4 * 256) {
            uint32_t v0 = eb[j], v1 = eb[j + 256], v2 = eb[j + 512], v3 = eb[j + 768];
            int p0 = atomicAdd(&cur[v0 >> 16], 1);
            int p1 = atomicAdd(&cur[v1 >> 16], 1);
            int p2 = atomicAdd(&cur[v2 >> 16], 1);
            int p3 = atomicAdd(&cur[v3 >> 16], 1);
            if (p0 < SLOT) colL[((v0 >> 16) << 6) + p0] = (uint16_t)(v0 & 0xffff);
            if (p1 < SLOT) colL[((v1 >> 16) << 6) + p1] = (uint16_t)(v1 & 0xffff);
            if (p2 < SLOT) colL[((v2 >> 16) << 6) + p2] = (uint16_t)(v2 & 0xffff);
            if (p3 < SLOT) colL[((v3 >> 16) << 6) + p3] = (uint16_t)(v3 & 0xffff);
        }
        for (; j < cn; j += 256) {
            uint32_t v = eb[j];
            int p = atomicAdd(&cur[v >> 16], 1);
            if (p < SLOT) colL[((v >> 16) << 6) + p] = (uint16_t)(v & 0xffff);
        }
        __syncthreads();
        int nodes = N_NODES - nbase; if (nodes > 256) nodes = 256;
        uint4* dstc = (uint4*)(col2 + ((size_t)nbase << 6));
        const uint4* srcc = (const uint4*)colL;
        for (int i = t; i < nodes * 8; i += 256)    // 8 uint4 per 64-slot row
            dstc[i] = srcc[i];
        int node = nbase + t;
        if (node < N_NODES) {
            int dg = cur[t];
            degc[node] = dg;
            dinv[node] = rsqrtf((float)dg + 1.0f);   // +1 self-loop
        }
        return;
    }

    // ================= gemm1 (unscaled output, f16 single-product) ==========
    char* As = sm;
    char* Bs = sm + ABYTES;

    const int lane = t & 63;
    const int w    = t >> 6;
    const int wrow = w & 1, wcol = w >> 1;
    const int m0   = (blockIdx.x - NBUCK) * BM;
    const int M    = N_NODES;

    const int sr = t >> 2, skq = t & 3;
    int arow = m0 + sr; if (arow > M - 1) arow = M - 1;
    const float* aptr = A + (size_t)arow * K + skq * 8;
    const int aslot = ((sr >> 4) * 64 + skq * 16 + (sr & 15)) * 16;

    f32x4 acc[2][CT];
#pragma unroll
    for (int rt = 0; rt < 2; ++rt)
#pragma unroll
        for (int ct = 0; ct < CT; ++ct) {
            f32x4 z = {0.f, 0.f, 0.f, 0.f};
            acc[rt][ct] = z;
        }

    const uint4* gh = (const uint4*)Bswz;

    constexpr int NCH = K / BK;
#pragma unroll 1
    for (int c = 0; c < NCH; ++c) {
        float4 v0 = *(const float4*)(aptr + c * BK);
        float4 v1 = *(const float4*)(aptr + c * BK + 4);
        uint4 bh0, bh1;
        {
            const uint4* ch = gh + (size_t)c * (BBYTES / 16);
            bh0 = ch[t];
            bh1 = ch[t + 256];
        }
        __syncthreads();
        {
            float e[8] = {v0.x, v0.y, v0.z, v0.w, v1.x, v1.y, v1.z, v1.w};
            uint32_t hp[4];
#pragma unroll
            for (int j = 0; j < 4; ++j)
                hp[j] = pack2h(e[2 * j], e[2 * j + 1]);
            *(uint4*)(As + aslot) = make_uint4(hp[0], hp[1], hp[2], hp[3]);
        }
        *(uint4*)(Bs + t * 16) = bh0;
        *(uint4*)(Bs + (t + 256) * 16) = bh1;
        __syncthreads();
        f16x8 Ah[2];
#pragma unroll
        for (int rt = 0; rt < 2; ++rt) {
            int st = wrow * 2 + rt;
            Ah[rt] = *(const f16x8*)(As + st * 1024 + lane * 16);
        }
#pragma unroll
        for (int ct = 0; ct < CT; ++ct) {
            int cg = wcol * CT + ct;
            f16x8 Bh = *(const f16x8*)(Bs + cg * 1024 + lane * 16);
#pragma unroll
            for (int rt = 0; rt < 2; ++rt)
                acc[rt][ct] = __builtin_amdgcn_mfma_f32_16x16x32_f16(Ah[rt], Bh, acc[rt][ct], 0, 0, 0);
        }
    }

#pragma unroll
    for (int rt = 0; rt < 2; ++rt) {
        int rowbase = m0 + wrow * 32 + rt * 16 + (lane >> 4) * 4;
#pragma unroll
        for (int ct = 0; ct < CT; ++ct) {
            int n = (wcol * CT + ct) * 16 + (lane & 15);
#pragma unroll
            for (int r = 0; r < 4; ++r) {
                int m = rowbase + r;
                if (m < M) out[(size_t)m * N + n] = f2h_bits(acc[rt][ct][r]);  // UNSCALED f16
            }
        }
    }
}

// ---------------------------------------------------------------------------
// FUSED TAIL (normal launch): gather1+gemm2 -> gbar -> gather2 -> gbar ->
// logits. 1024 blocks (4/CU co-resident), grid-stride phases, load-spin
// software barrier. Phase bodies identical to the R8-verified kernels.
// ---------------------------------------------------------------------------
__global__ __launch_bounds__(256, 4) void fused_tail_kernel(
        const uint16_t* __restrict__ col2, const int* __restrict__ degc,
        const uint16_t* __restrict__ h0u, const float* __restrict__ dinv,
        const float* __restrict__ b1,  const uint16_t* __restrict__ B2swz,
        uint16_t* __restrict__ z0s, const float* __restrict__ b2,
        uint16_t* __restrict__ zbuf,
        const int* __restrict__ pos, const int* __restrict__ neg,
        float* __restrict__ out, int* gbar) {
    __shared__ uint4 hlds[256];
    const int t    = threadIdx.x;
    const int lane = t & 63;
    const int w    = t >> 6;

    // ================= PHASE A: gather1 + gemm2 =================
    {
        const int sub  = lane >> 4;             // node within wave (0..3)
        const int l    = lane & 15;             // feature octet (0..15)
        const int node_loc = w * 4 + sub;
        const uint4* hs4 = (const uint4*)h0u;
        const uint32_t* cp = (const uint32_t*)col2;
        const int sb = sub * 16;

        for (int grp = blockIdx.x; grp < GG_GROUPS; grp += TAIL_BLOCKS) {
            const int node = grp * 16 + node_loc;   // exact: 3125*16=50000
            int dg = degc[node]; if (dg > SLOT) dg = SLOT;
            const float dn = dinv[node];
            float a0[8], a1[8];
#pragma unroll
            for (int i = 0; i < 8; ++i) { a0[i] = 0.f; a1[i] = 0.f; }
            {
                uint4 self = hs4[(size_t)node * 16 + l];
                acc_h8s(a0, self, dn);          // self message * dinv[node]
            }
            const int pbase = node * (SLOT / 2);

            for (int c = 0; c * 16 < dg; ++c) {
                int cnt = dg - c * 16; if (cnt > 16) cnt = 16;
                uint32_t cv = (2 * l < cnt) ? cp[pbase + c * 8 + l] : 0u;
                int j = 0;
                for (; j + 8 <= cnt; j += 8) {
                    uint32_t p0 = (uint32_t)__shfl((int)cv, sb + (j >> 1),     64);
                    uint32_t p1 = (uint32_t)__shfl((int)cv, sb + (j >> 1) + 1, 64);
                    uint32_t p2 = (uint32_t)__shfl((int)cv, sb + (j >> 1) + 2, 64);
                    uint32_t p3 = (uint32_t)__shfl((int)cv, sb + (j >> 1) + 3, 64);
                    int s0 = p0 & 0xffff, s1 = p0 >> 16;
                    int s2 = p1 & 0xffff, s3 = p1 >> 16;
                    int s4 = p2 & 0xffff, s5 = p2 >> 16;
                    int s6 = p3 & 0xffff, s7 = p3 >> 16;
                    uint4 v0 = hs4[(size_t)s0 * 16 + l];
                    uint4 v1 = hs4[(size_t)s1 * 16 + l];
                    uint4 v2 = hs4[(size_t)s2 * 16 + l];
                    uint4 v3 = hs4[(size_t)s3 * 16 + l];
                    uint4 v4 = hs4[(size_t)s4 * 16 + l];
                    uint4 v5 = hs4[(size_t)s5 * 16 + l];
                    uint4 v6 = hs4[(size_t)s6 * 16 + l];
                    uint4 v7 = hs4[(size_t)s7 * 16 + l];
                    float d0 = dinv[s0], d1 = dinv[s1], d2 = dinv[s2], d3 = dinv[s3];
                    float d4 = dinv[s4], d5 = dinv[s5], d6 = dinv[s6], d7 = dinv[s7];
                    acc_h8s(a0, v0, d0); acc_h8s(a1, v1, d1);
                    acc_h8s(a0, v2, d2); acc_h8s(a1, v3, d3);
                    acc_h8s(a0, v4, d4); acc_h8s(a1, v5, d5);
                    acc_h8s(a0, v6, d6); acc_h8s(a1, v7, d7);
                }
                for (; j + 4 <= cnt; j += 4) {
                    uint32_t p0 = (uint32_t)__shfl((int)cv, sb + (j >> 1),     64);
                    uint32_t p1 = (uint32_t)__shfl((int)cv, sb + (j >> 1) + 1, 64);
                    int s0 = p0 & 0xffff, s1 = p0 >> 16;
                    int s2 = p1 & 0xffff, s3 = p1 >> 16;
                    uint4 v0 = hs4[(size_t)s0 * 16 + l];
                    uint4 v1 = hs4[(size_t)s1 * 16 + l];
                    uint4 v2 = hs4[(size_t)s2 * 16 + l];
                    uint4 v3 = hs4[(size_t)s3 * 16 + l];
                    float d0 = dinv[s0], d1 = dinv[s1], d2 = dinv[s2], d3 = dinv[s3];
                    acc_h8s(a0, v0, d0); acc_h8s(a1, v1, d1);
                    acc_h8s(a0, v2, d2); acc_h8s(a1, v3, d3);
                }
                for (; j < cnt; ++j) {
                    uint32_t p = (uint32_t)__shfl((int)cv, sb + (j >> 1), 64);
                    int s = (j & 1) ? (int)(p >> 16) : (int)(p & 0xffff);
                    uint4 v = hs4[(size_t)s * 16 + l];
                    acc_h8s(a0, v, dinv[s]);
                }
            }
            {
                float4 bb0 = ((const float4*)b1)[2 * l];
                float4 bb1 = ((const float4*)b1)[2 * l + 1];
                float o[8];
                o[0] = fmaxf((a0[0] + a1[0]) * dn + bb0.x, 0.f);
                o[1] = fmaxf((a0[1] + a1[1]) * dn + bb0.y, 0.f);
                o[2] = fmaxf((a0[2] + a1[2]) * dn + bb0.z, 0.f);
                o[3] = fmaxf((a0[3] + a1[3]) * dn + bb0.w, 0.f);
                o[4] = fmaxf((a0[4] + a1[4]) * dn + bb1.x, 0.f);
                o[5] = fmaxf((a0[5] + a1[5]) * dn + bb1.y, 0.f);
                o[6] = fmaxf((a0[6] + a1[6]) * dn + bb1.z, 0.f);
                o[7] = fmaxf((a0[7] + a1[7]) * dn + bb1.w, 0.f);
                hlds[l * 16 + node_loc] = make_uint4(
                    pack2h(o[0], o[1]), pack2h(o[2], o[3]),
                    pack2h(o[4], o[5]), pack2h(o[6], o[7]));
            }
            __syncthreads();

            // gemm2: z0 tile = h(16x128) @ W2 — f16 single
            f32x4 acc = {0.f, 0.f, 0.f, 0.f};
            const char* hb = (const char*)hlds;
#pragma unroll
            for (int c = 0; c < 4; ++c) {
                f16x8 Af = *(const f16x8*)(hb + c * 1024 + lane * 16);
                f16x8 Bh = *(const f16x8*)(B2swz + (c * 4 + w) * 512 + lane * 8);
                acc = __builtin_amdgcn_mfma_f32_16x16x32_f16(Af, Bh, acc, 0, 0, 0);
            }
            const int colg = w * 16 + (lane & 15);
            const int rowb = grp * 16 + (lane >> 4) * 4;
#pragma unroll
            for (int r = 0; r < 4; ++r) {
                int m = rowb + r;
                z0s[(size_t)m * C_OUT + colg] = f2h_bits(acc[r] * dinv[m]);
            }
            __syncthreads();    // hlds reused next grid-stride iteration
        }
    }
    global_barrier(gbar + 0, TAIL_BLOCKS);

    // ================= PHASE B: gather2 (z = A_norm z0' + b2) =================
    {
        constexpr int LPN = C_OUT / 8;      // 8 lanes per node
        constexpr int NPW = 64 / LPN;       // 8 nodes per wave
        const int sub  = lane / LPN;        // 0..7
        const int l    = lane % LPN;        // feature octet (0..7)
        const uint4* hs4 = (const uint4*)z0s;
        const uint32_t* cp = (const uint32_t*)col2;
        const int sb = sub * LPN;

        for (int grp = blockIdx.x; grp < G2_GROUPS; grp += TAIL_BLOCKS) {
            const int node = grp * (4 * NPW) + w * NPW + sub;
            if (node < N_NODES) {
                int dg = degc[node]; if (dg > SLOT) dg = SLOT;
                float a0[8], a1[8];
#pragma unroll
                for (int i = 0; i < 8; ++i) { a0[i] = 0.f; a1[i] = 0.f; }
                {
                    uint4 self = hs4[(size_t)node * LPN + l];
                    acc_h8(a0, self);
                }
                const int pbase = node * (SLOT / 2);

                for (int c = 0; c * LPN < dg; ++c) {
                    int cnt = dg - c * LPN; if (cnt > LPN) cnt = LPN;
                    uint32_t cv = (2 * l < cnt) ? cp[pbase + c * (LPN / 2) + l] : 0u;
                    int j = 0;
                    for (; j + 8 <= cnt; j += 8) {
                        uint32_t p0 = (uint32_t)__shfl((int)cv, sb + (j >> 1),     64);
                        uint32_t p1 = (uint32_t)__shfl((int)cv, sb + (j >> 1) + 1, 64);
                        uint32_t p2 = (uint32_t)__shfl((int)cv, sb + (j >> 1) + 2, 64);
                        uint32_t p3 = (uint32_t)__shfl((int)cv, sb + (j >> 1) + 3, 64);
                        int s0 = p0 & 0xffff, s1 = p0 >> 16;
                        int s2 = p1 & 0xffff, s3 = p1 >> 16;
                        int s4 = p2 & 0xffff, s5 = p2 >> 16;
                        int s6 = p3 & 0xffff, s7 = p3 >> 16;
                        uint4 v0 = hs4[(size_t)s0 * LPN + l];
                        uint4 v1 = hs4[(size_t)s1 * LPN + l];
                        uint4 v2 = hs4[(size_t)s2 * LPN + l];
                        uint4 v3 = hs4[(size_t)s3 * LPN + l];
                        uint4 v4 = hs4[(size_t)s4 * LPN + l];
                        uint4 v5 = hs4[(size_t)s5 * LPN + l];
                        uint4 v6 = hs4[(size_t)s6 * LPN + l];
                        uint4 v7 = hs4[(size_t)s7 * LPN + l];
                        acc_h8(a0, v0); acc_h8(a1, v1);
                        acc_h8(a0, v2); acc_h8(a1, v3);
                        acc_h8(a0, v4); acc_h8(a1, v5);
                        acc_h8(a0, v6); acc_h8(a1, v7);
                    }
                    for (; j + 4 <= cnt; j += 4) {
                        uint32_t p0 = (uint32_t)__shfl((int)cv, sb + (j >> 1),     64);
                        uint32_t p1 = (uint32_t)__shfl((int)cv, sb + (j >> 1) + 1, 64);
                        int s0 = p0 & 0xffff, s1 = p0 >> 16;
                        int s2 = p1 & 0xffff, s3 = p1 >> 16;
                        uint4 v0 = hs4[(size_t)s0 * LPN + l];
                        uint4 v1 = hs4[(size_t)s1 * LPN + l];
                        uint4 v2 = hs4[(size_t)s2 * LPN + l];
                        uint4 v3 = hs4[(size_t)s3 * LPN + l];
                        acc_h8(a0, v0); acc_h8(a1, v1);
                        acc_h8(a0, v2); acc_h8(a1, v3);
                    }
                    for (; j < cnt; ++j) {
                        uint32_t p = (uint32_t)__shfl((int)cv, sb + (j >> 1), 64);
                        int s = (j & 1) ? (int)(p >> 16) : (int)(p & 0xffff);
                        uint4 v = hs4[(size_t)s * LPN + l];
                        acc_h8(a0, v);
                    }
                }

                const float dn = dinv[node];
                float4 bb0 = ((const float4*)b2)[2 * l];
                float4 bb1 = ((const float4*)b2)[2 * l + 1];
                float o[8];
                o[0] = (a0[0] + a1[0]) * dn + bb0.x;
                o[1] = (a0[1] + a1[1]) * dn + bb0.y;
                o[2] = (a0[2] + a1[2]) * dn + bb0.z;
                o[3] = (a0[3] + a1[3]) * dn + bb0.w;
                o[4] = (a0[4] + a1[4]) * dn + bb1.x;
                o[5] = (a0[5] + a1[5]) * dn + bb1.y;
                o[6] = (a0[6] + a1[6]) * dn + bb1.z;
                o[7] = (a0[7] + a1[7]) * dn + bb1.w;
                uint4 res = make_uint4(pack2h(o[0], o[1]), pack2h(o[2], o[3]),
                                       pack2h(o[4], o[5]), pack2h(o[6], o[7]));
                ((uint4*)zbuf)[(size_t)node * LPN + l] = res;
            }
        }
    }
    global_barrier(gbar + 1, TAIL_BLOCKS);

    // ================= PHASE C: logits =================
    {
        const int l = t & 7;
        const uint4* z4 = (const uint4*)zbuf;
        for (int vb = blockIdx.x; vb < LG_GROUPS; vb += TAIL_BLOCKS) {
            const int g = (vb * 256 + t) >> 3;      // edge-pair id
            const int e0 = 2 * g;
            if (e0 < 2 * E_PAIR) {
                int s0, d0, s1, d1;
                if (e0 < E_PAIR) { s0 = pos[e0];          d0 = pos[E_PAIR + e0]; }
                else             { s0 = neg[e0 - E_PAIR]; d0 = neg[e0];          }
                int e1 = e0 + 1;
                if (e1 < E_PAIR) { s1 = pos[e1];          d1 = pos[E_PAIR + e1]; }
                else             { s1 = neg[e1 - E_PAIR]; d1 = neg[e1];          }
                uint4 ua0 = z4[(size_t)s0 * 8 + l];
                uint4 ub0 = z4[(size_t)d0 * 8 + l];
                uint4 ua1 = z4[(size_t)s1 * 8 + l];
                uint4 ub1 = z4[(size_t)d1 * 8 + l];
                float v0 = dot_h8(ua0, ub0);
                float v1 = dot_h8(ua1, ub1);
                v0 += __shfl_xor(v0, 1, 64); v1 += __shfl_xor(v1, 1, 64);
                v0 += __shfl_xor(v0, 2, 64); v1 += __shfl_xor(v1, 2, 64);
                v0 += __shfl_xor(v0, 4, 64); v1 += __shfl_xor(v1, 4, 64);
                if (l == 0) { out[e0] = v0; out[e1] = v1; }
            }
        }
    }
}

// ---------------------------------------------------------------------------
extern "C" void kernel_launch(void* const* d_in, const int* in_sizes, int n_in,
                              void* d_out, int out_size, void* d_ws, size_t ws_size,
                              hipStream_t stream) {
    const float* x   = (const float*)d_in[0];
    const int*   ei  = (const int*)d_in[1];   // [2, E] : row0=src, row1=dst
    const int*   pos = (const int*)d_in[2];   // [2, E_PAIR]
    const int*   neg = (const int*)d_in[3];   // [2, E_PAIR]
    const float* W1  = (const float*)d_in[4];
    const float* b1  = (const float*)d_in[5];
    const float* W2  = (const float*)d_in[6];
    const float* b2  = (const float*)d_in[7];
    float* out = (float*)d_out;

    const int* src = ei;
    const int* dst = ei + E_EDGES;

    // Workspace layout (byte offsets, 256B-aligned):
    //   degc @0 (200704) | dinv @200704 (200704) | col2 @401408 (6.4MB u16)
    //   gcur @6801408 (784B) | gbar @6802192 (8B) | B1swz @6802432 (64KB used)
    //   B2swz @6933504 (16KB used) | h0u @6966272 (12.8MB f16, UNSCALED)
    //   z0s @32566272 (6.4MB f16) | z @38966272 (6.4MB f16)
    //   ebuf @45366272 (3.7MB u32) -> ~49MB
    char* ws = (char*)d_ws;
    int*      degc  = (int*)ws;
    float*    dinv  = (float*)(ws + 200704);
    uint16_t* col2  = (uint16_t*)(ws + 401408);
    int*      gcur  = (int*)(ws + 6801408);
    int*      gbar  = (int*)(ws + 6802192);
    uint16_t* B1swz = (uint16_t*)(ws + 6802432);
    uint16_t* B2swz = (uint16_t*)(ws + 6933504);
    uint16_t* h0u   = (uint16_t*)(ws + 6966272);
    uint16_t* z0s   = (uint16_t*)(ws + 32566272);
    uint16_t* zbuf  = (uint16_t*)(ws + 38966272);
    uint32_t* ebuf  = (uint32_t*)(ws + 45366272);

    // 0. zero bucket cursors AND barrier counters (792 B, graph-capturable;
    //    re-runs on every graph replay so the barrier resets each launch)
    hipMemsetAsync(gcur, 0, 792, stream);

    // 1. MERGED prep (W1/W2 -> f16 swizzle) + binA (LDS-binned edge pass)
    prep_binA_kernel<<<PREPB + BINAB, 256, 0, stream>>>(
        W1, W2, B1swz, B2swz, src, dst, gcur, ebuf);

    // 2. MERGED: binB LDS-staged (196 blocks) + gemm1-unscaled (782 blocks)
    build_gemm_kernel<<<NBUCK + GEMM1_BLOCKS, 256, 0, stream>>>(
        gcur, ebuf, col2, degc, dinv, x, B1swz, h0u);

    // 3. FUSED TAIL (normal launch, load-spin software grid barrier):
    //    gather1+gemm2 -> bar -> gather2 -> bar -> logits
    fused_tail_kernel<<<TAIL_BLOCKS, 256, 0, stream>>>(
        col2, degc, h0u, dinv, b1, B2swz, z0s, b2, zbuf, pos, neg, out, gbar);
}

// Round 12
// 190.462 us; speedup vs baseline: 3.1736x; 3.1736x over previous
//
#include <hip/hip_runtime.h>
#include <stdint.h>

// Problem constants (from reference setup_inputs)
constexpr int N_NODES = 50000;
constexpr int E_EDGES = 800000;
constexpr int E_PAIR  = 200000;   // pos edges; neg edges same count
constexpr int C_IN    = 256;
constexpr int C_HID   = 128;
constexpr int C_OUT   = 64;
constexpr int SLOT    = 64;       // fixed CSR slot; max degree ~45 (Poisson 16)

// Two-phase binned build (196 buckets of 256 nodes)
constexpr int NBUCK = 196;        // dst >> 8  (196*256 = 50176 >= 50000)
constexpr int BCAP  = 4608;       // per-bucket capacity (mean 4082, ~8 sigma)
constexpr int CHUNK = 4096;       // edges per binA block (84B runs -> coalesced)
constexpr int PREPB = 32;         // prep blocks merged into binA dispatch
constexpr int BINAB = (E_EDGES + CHUNK - 1) / CHUNK;   // 196
constexpr int GEMM1_BLOCKS = (N_NODES + 63) / 64;      // 782

typedef __attribute__((ext_vector_type(8))) _Float16 f16x8;  // 8 f16 (4 VGPRs)
typedef __attribute__((ext_vector_type(2))) _Float16 f16x2;
typedef __attribute__((ext_vector_type(4))) float f32x4;

__device__ inline uint16_t f2h_bits(float v) {             // RNE fp32->f16 bits
    union { _Float16 h; uint16_t u; } c; c.h = (_Float16)v;
    return c.u;
}
__device__ inline uint32_t pack2h(float a, float b) {
    return (uint32_t)f2h_bits(a) | ((uint32_t)f2h_bits(b) << 16);
}
// accumulate 8 f16 (uint4) into 8 fp32 — cvt+add / fma_mix path
__device__ inline void acc_h8(float* a, uint4 v) {
    union { uint4 u; _Float16 h[8]; } c; c.u = v;
#pragma unroll
    for (int i = 0; i < 8; ++i) a[i] += (float)c.h[i];
}
// accumulate 8 f16 scaled by s into 8 fp32 — targets v_fma_mix_f32
__device__ inline void acc_h8s(float* a, uint4 v, float s) {
    union { uint4 u; _Float16 h[8]; } c; c.u = v;
#pragma unroll
    for (int i = 0; i < 8; ++i) a[i] += (float)c.h[i] * s;
}
__device__ inline float dot_h8(uint4 a, uint4 b) {
    union { uint4 u; f16x2 h[4]; } ca, cb; ca.u = a; cb.u = b;
    float v = 0.f;
#pragma unroll
    for (int i = 0; i < 4; ++i) {
#if __has_builtin(__builtin_amdgcn_fdot2)
        v = __builtin_amdgcn_fdot2(ca.h[i], cb.h[i], v, false);
#else
        v += (float)ca.h[i][0] * (float)cb.h[i][0]
           + (float)ca.h[i][1] * (float)cb.h[i][1];
#endif
    }
    return v;
}

// W swizzle index (MFMA B-frag order)
template<int N>
__device__ inline int wswz_idx(int k, int n) {
    int c = k >> 5, kq = (k >> 3) & 3, kk = k & 7, ct = n >> 4, nn = n & 15;
    return (((c * (N / 16) + ct) * 4 + kq) * 16 + nn) * 8 + kk;
}

// ---------------------------------------------------------------------------
// MERGED prep + binA:
//   blocks [0, PREPB):  W1/W2 -> f16 swizzle (grid-stride)
//   blocks [PREPB, +BINAB): LDS-bin 4096 edges by dst>>8. Staged records pack
//   bucket in bits 24-31: (b<<24)|(dloc<<16)|src — so the bucket-contiguous
//   write loop needs no side array, and ebuf stores the low 24 bits
//   (binB's v>>16 == dloc semantics unchanged).
// gcur is zeroed by a tiny hipMemsetAsync before this dispatch.
// ---------------------------------------------------------------------------
__global__ __launch_bounds__(256) void prep_binA_kernel(
        const float* __restrict__ W1, const float* __restrict__ W2,
        uint16_t* __restrict__ s1, uint16_t* __restrict__ s2,
        const int* __restrict__ src, const int* __restrict__ dst,
        int* __restrict__ gcur, uint32_t* __restrict__ ebuf) {
    __shared__ int cnt[NBUCK], loc[NBUCK], lim[NBUCK], abase[NBUCK], wcur[NBUCK];
    __shared__ int tot;
    __shared__ uint32_t stag[CHUNK];            // 16 KB

    const int t = threadIdx.x;

    if (blockIdx.x < PREPB) {
        for (int id = blockIdx.x * 256 + t;
             id < C_IN * C_HID + C_HID * C_OUT; id += PREPB * 256) {
            if (id < C_IN * C_HID) {
                int idx = wswz_idx<C_HID>(id / C_HID, id & (C_HID - 1));
                s1[idx] = f2h_bits(W1[id]);
            } else {
                int id2 = id - C_IN * C_HID;
                int idx = wswz_idx<C_OUT>(id2 / C_OUT, id2 & (C_OUT - 1));
                s2[idx] = f2h_bits(W2[id2]);
            }
        }
        return;
    }

    const int e0 = (blockIdx.x - PREPB) * CHUNK;
    const int n  = min(CHUNK, E_EDGES - e0);

    for (int b = t; b < NBUCK; b += 256) cnt[b] = 0;
    if (t == 0) tot = 0;
    __syncthreads();

    uint32_t pk[CHUNK / 256];                   // 16 regs
    int ne = 0;
    for (int j = t; j < n; j += 256) {
        int d = dst[e0 + j], s = src[e0 + j];
        int b = d >> 8;
        pk[ne] = ((uint32_t)b << 24) | ((uint32_t)(d & 255) << 16) | (uint32_t)s;
        atomicAdd(&cnt[b], 1);
        ++ne;
    }
    __syncthreads();
    for (int b = t; b < NBUCK; b += 256)
        loc[b] = atomicAdd(&tot, cnt[b]);       // unordered contiguous packing
    __syncthreads();
    for (int b = t; b < NBUCK; b += 256) {
        int base = atomicAdd(&gcur[b], cnt[b]);
        int room = BCAP - base; if (room < 0) room = 0;
        lim[b]   = loc[b] + room;
        abase[b] = b * BCAP + base - loc[b];
        wcur[b]  = loc[b];
    }
    __syncthreads();
#pragma unroll
    for (int i = 0; i < CHUNK / 256; ++i) {
        if (i < ne) {
            int p = atomicAdd(&wcur[pk[i] >> 24], 1);
            stag[p] = pk[i];
        }
    }
    __syncthreads();
    for (int j = t; j < n; j += 256) {
        uint32_t v = stag[j];
        int b = v >> 24;
        if (j < lim[b]) ebuf[abase[b] + j] = v & 0x00ffffffu;
    }
}

// ---------------------------------------------------------------------------
// MERGED binB + gemm1: blocks [0,196) do binB, [196, 196+782) do gemm1.
// binB builds its bucket's col2 slice in LDS (256 nodes x 64 slots x u16
// = 32 KB, LDS-atomic slot counters) and copies it out COALESCED — replaces
// 800K scattered global u16 writes with streaming 512B/wave stores.
// gemm1 single-MFMA f16: A = f16(x), B = f16(W1). h0u stored UNSCALED f16.
// ---------------------------------------------------------------------------
__global__ __launch_bounds__(256, 3) void build_gemm_kernel(
        // binB args
        const int* __restrict__ gcur, const uint32_t* __restrict__ ebuf,
        uint16_t* __restrict__ col2, int* __restrict__ degc,
        float* __restrict__ dinv,
        // gemm1 args (K=C_IN, N=C_HID)
        const float* __restrict__ A, const uint16_t* __restrict__ Bswz,
        uint16_t* __restrict__ out) {
    constexpr int K = C_IN, N = C_HID;
    constexpr int BM = 64, BK = 32;
    constexpr int CT   = N / 32;            // 4
    constexpr int NSUB = N / 16;            // 8
    constexpr int ABYTES = BM * BK * 2;     // 4096
    constexpr int BBYTES = NSUB * 1024;     // 8192
    // binB needs 1KB counters + 32KB col staging = 33KB; gemm1 needs 12.25KB
    __shared__ char sm[1024 + 256 * SLOT * 2];   // 33 KB

    const int t = threadIdx.x;

    if (blockIdx.x < NBUCK) {
        // ================= binB (LDS-staged col2) =================
        int* cur = (int*)sm;                        // 256 counters
        uint16_t* colL = (uint16_t*)(sm + 1024);    // 256 x 64 u16
        const int b = blockIdx.x;
        cur[t] = 0;
        __syncthreads();

        int cn = gcur[b]; if (cn > BCAP) cn = BCAP;
        const uint32_t* eb = ebuf + (size_t)b * BCAP;
        const int nbase = b << 8;

        int j = t;
        for (; j + 3 * 256 < cn; j += 4 * 256) {
            uint32_t v0 = eb[j], v1 = eb[j + 256], v2 = eb[j + 512], v3 = eb[j + 768];
            int p0 = atomicAdd(&cur[v0 >> 16], 1);
            int p1 = atomicAdd(&cur[v1 >> 16], 1);
            int p2 = atomicAdd(&cur[v2 >> 16], 1);
            int p3 = atomicAdd(&cur[v3 >> 16], 1);
            if (p0 < SLOT) colL[((v0 >> 16) << 6) + p0] = (uint16_t)(v0 & 0xffff);
            if (p1 < SLOT) colL[((v1 >> 16) << 6) + p1] = (uint16_t)(v1 & 0xffff);
            if (p2 < SLOT) colL[((v2 >> 16) << 6) + p2] = (uint16_t)(v2 & 0xffff);
            if (p3 < SLOT) colL[((v3 >> 16) << 6) + p3] = (uint16_t)(v3 & 0xffff);
        }
        for (; j < cn; j += 256) {
            uint32_t v = eb[j];
            int p = atomicAdd(&cur[v >> 16], 1);
            if (p < SLOT) colL[((v >> 16) << 6) + p] = (uint16_t)(v & 0xffff);
        }
        __syncthreads();
        // coalesced copy-out, bounded so bucket 195 can't overrun col2
        int nodes = N_NODES - nbase; if (nodes > 256) nodes = 256;
        uint4* dstc = (uint4*)(col2 + ((size_t)nbase << 6));
        const uint4* srcc = (const uint4*)colL;
        for (int i = t; i < nodes * 8; i += 256)    // 8 uint4 per 64-slot row
            dstc[i] = srcc[i];
        int node = nbase + t;
        if (node < N_NODES) {
            int dg = cur[t];
            degc[node] = dg;
            dinv[node] = rsqrtf((float)dg + 1.0f);   // +1 self-loop
        }
        return;
    }

    // ================= gemm1 (unscaled output, f16 single-product) ==========
    char* As = sm;
    char* Bs = sm + ABYTES;

    const int lane = t & 63;
    const int w    = t >> 6;
    const int wrow = w & 1, wcol = w >> 1;
    const int m0   = (blockIdx.x - NBUCK) * BM;
    const int M    = N_NODES;

    const int sr = t >> 2, skq = t & 3;
    int arow = m0 + sr; if (arow > M - 1) arow = M - 1;
    const float* aptr = A + (size_t)arow * K + skq * 8;
    const int aslot = ((sr >> 4) * 64 + skq * 16 + (sr & 15)) * 16;

    f32x4 acc[2][CT];
#pragma unroll
    for (int rt = 0; rt < 2; ++rt)
#pragma unroll
        for (int ct = 0; ct < CT; ++ct) {
            f32x4 z = {0.f, 0.f, 0.f, 0.f};
            acc[rt][ct] = z;
        }

    const uint4* gh = (const uint4*)Bswz;

    constexpr int NCH = K / BK;
#pragma unroll 1
    for (int c = 0; c < NCH; ++c) {
        float4 v0 = *(const float4*)(aptr + c * BK);
        float4 v1 = *(const float4*)(aptr + c * BK + 4);
        uint4 bh0, bh1;
        {
            const uint4* ch = gh + (size_t)c * (BBYTES / 16);
            bh0 = ch[t];
            bh1 = ch[t + 256];
        }
        __syncthreads();
        {
            float e[8] = {v0.x, v0.y, v0.z, v0.w, v1.x, v1.y, v1.z, v1.w};
            uint32_t hp[4];
#pragma unroll
            for (int j = 0; j < 4; ++j)
                hp[j] = pack2h(e[2 * j], e[2 * j + 1]);
            *(uint4*)(As + aslot) = make_uint4(hp[0], hp[1], hp[2], hp[3]);
        }
        *(uint4*)(Bs + t * 16) = bh0;
        *(uint4*)(Bs + (t + 256) * 16) = bh1;
        __syncthreads();
        f16x8 Ah[2];
#pragma unroll
        for (int rt = 0; rt < 2; ++rt) {
            int st = wrow * 2 + rt;
            Ah[rt] = *(const f16x8*)(As + st * 1024 + lane * 16);
        }
#pragma unroll
        for (int ct = 0; ct < CT; ++ct) {
            int cg = wcol * CT + ct;
            f16x8 Bh = *(const f16x8*)(Bs + cg * 1024 + lane * 16);
#pragma unroll
            for (int rt = 0; rt < 2; ++rt)
                acc[rt][ct] = __builtin_amdgcn_mfma_f32_16x16x32_f16(Ah[rt], Bh, acc[rt][ct], 0, 0, 0);
        }
    }

#pragma unroll
    for (int rt = 0; rt < 2; ++rt) {
        int rowbase = m0 + wrow * 32 + rt * 16 + (lane >> 4) * 4;
#pragma unroll
        for (int ct = 0; ct < CT; ++ct) {
            int n = (wcol * CT + ct) * 16 + (lane & 15);
#pragma unroll
            for (int r = 0; r < 4; ++r) {
                int m = rowbase + r;
                if (m < M) out[(size_t)m * N + n] = f2h_bits(acc[rt][ct][r]);  // UNSCALED f16
            }
        }
    }
}

// ---------------------------------------------------------------------------
// FUSED gather1 + gemm2, deferred-dinv, ONE-TEAM (R6 verified): 256 threads
// = 16 nodes/block, 16 lanes/node. col2 read PACKED (2 ids per uint):
// 4 ds_bpermute per 8-edge batch. f16 rows, fma_mix accumulate.
// ---------------------------------------------------------------------------
__global__ __launch_bounds__(256) void gather_gemm_kernel(
        const uint16_t* __restrict__ col2, const int* __restrict__ degc,
        const uint16_t* __restrict__ h0u, const float* __restrict__ dinv,
        const float* __restrict__ bias, const uint16_t* __restrict__ B2swz,
        uint16_t* __restrict__ z0s) {
    __shared__ uint4 hlds[256];                 // [oct 0..15][row 0..15] (f16 pairs)
    const int t    = threadIdx.x;
    const int lane = t & 63;
    const int w    = t >> 6;                    // wave 0..3
    const int sub  = lane >> 4;                 // node within wave (0..3)
    const int l    = lane & 15;                 // feature octet (0..15)
    const int node_loc = w * 4 + sub;
    const int node = blockIdx.x * 16 + node_loc;  // grid exact: 3125*16=50000

    int dg = degc[node]; if (dg > SLOT) dg = SLOT;
    const float dn = dinv[node];
    const uint4* hs4 = (const uint4*)h0u;
    float a0[8], a1[8];
#pragma unroll
    for (int i = 0; i < 8; ++i) { a0[i] = 0.f; a1[i] = 0.f; }
    {
        uint4 self = hs4[(size_t)node * 16 + l];
        acc_h8s(a0, self, dn);                  // self message * dinv[node]
    }
    const uint32_t* cp = (const uint32_t*)col2;
    const int pbase = node * (SLOT / 2);        // uint index of row start
    const int sb    = sub * 16;                 // shfl base (this node's lane 0)

    for (int c = 0; c * 16 < dg; ++c) {
        int cnt = dg - c * 16; if (cnt > 16) cnt = 16;
        uint32_t cv = (2 * l < cnt) ? cp[pbase + c * 8 + l] : 0u;
        int j = 0;
        for (; j + 8 <= cnt; j += 8) {
            uint32_t p0 = (uint32_t)__shfl((int)cv, sb + (j >> 1),     64);
            uint32_t p1 = (uint32_t)__shfl((int)cv, sb + (j >> 1) + 1, 64);
            uint32_t p2 = (uint32_t)__shfl((int)cv, sb + (j >> 1) + 2, 64);
            uint32_t p3 = (uint32_t)__shfl((int)cv, sb + (j >> 1) + 3, 64);
            int s0 = p0 & 0xffff, s1 = p0 >> 16;
            int s2 = p1 & 0xffff, s3 = p1 >> 16;
            int s4 = p2 & 0xffff, s5 = p2 >> 16;
            int s6 = p3 & 0xffff, s7 = p3 >> 16;
            uint4 v0 = hs4[(size_t)s0 * 16 + l];
            uint4 v1 = hs4[(size_t)s1 * 16 + l];
            uint4 v2 = hs4[(size_t)s2 * 16 + l];
            uint4 v3 = hs4[(size_t)s3 * 16 + l];
            uint4 v4 = hs4[(size_t)s4 * 16 + l];
            uint4 v5 = hs4[(size_t)s5 * 16 + l];
            uint4 v6 = hs4[(size_t)s6 * 16 + l];
            uint4 v7 = hs4[(size_t)s7 * 16 + l];
            float d0 = dinv[s0], d1 = dinv[s1], d2 = dinv[s2], d3 = dinv[s3];
            float d4 = dinv[s4], d5 = dinv[s5], d6 = dinv[s6], d7 = dinv[s7];
            acc_h8s(a0, v0, d0); acc_h8s(a1, v1, d1);
            acc_h8s(a0, v2, d2); acc_h8s(a1, v3, d3);
            acc_h8s(a0, v4, d4); acc_h8s(a1, v5, d5);
            acc_h8s(a0, v6, d6); acc_h8s(a1, v7, d7);
        }
        for (; j + 4 <= cnt; j += 4) {
            uint32_t p0 = (uint32_t)__shfl((int)cv, sb + (j >> 1),     64);
            uint32_t p1 = (uint32_t)__shfl((int)cv, sb + (j >> 1) + 1, 64);
            int s0 = p0 & 0xffff, s1 = p0 >> 16;
            int s2 = p1 & 0xffff, s3 = p1 >> 16;
            uint4 v0 = hs4[(size_t)s0 * 16 + l];
            uint4 v1 = hs4[(size_t)s1 * 16 + l];
            uint4 v2 = hs4[(size_t)s2 * 16 + l];
            uint4 v3 = hs4[(size_t)s3 * 16 + l];
            float d0 = dinv[s0], d1 = dinv[s1], d2 = dinv[s2], d3 = dinv[s3];
            acc_h8s(a0, v0, d0); acc_h8s(a1, v1, d1);
            acc_h8s(a0, v2, d2); acc_h8s(a1, v3, d3);
        }
        for (; j < cnt; ++j) {
            uint32_t p = (uint32_t)__shfl((int)cv, sb + (j >> 1), 64);
            int s = (j & 1) ? (int)(p >> 16) : (int)(p & 0xffff);
            uint4 v = hs4[(size_t)s * 16 + l];
            acc_h8s(a0, v, dinv[s]);
        }
    }
    {
        float4 bb0 = ((const float4*)bias)[2 * l];
        float4 bb1 = ((const float4*)bias)[2 * l + 1];
        float o[8];
        o[0] = fmaxf((a0[0] + a1[0]) * dn + bb0.x, 0.f);
        o[1] = fmaxf((a0[1] + a1[1]) * dn + bb0.y, 0.f);
        o[2] = fmaxf((a0[2] + a1[2]) * dn + bb0.z, 0.f);
        o[3] = fmaxf((a0[3] + a1[3]) * dn + bb0.w, 0.f);
        o[4] = fmaxf((a0[4] + a1[4]) * dn + bb1.x, 0.f);
        o[5] = fmaxf((a0[5] + a1[5]) * dn + bb1.y, 0.f);
        o[6] = fmaxf((a0[6] + a1[6]) * dn + bb1.z, 0.f);
        o[7] = fmaxf((a0[7] + a1[7]) * dn + bb1.w, 0.f);
        hlds[l * 16 + node_loc] = make_uint4(
            pack2h(o[0], o[1]), pack2h(o[2], o[3]),
            pack2h(o[4], o[5]), pack2h(o[6], o[7]));
    }
    __syncthreads();

    // MFMA phase: z0 tile = h(16x128) @ W2(128 x [w*16..w*16+16)) — f16 single
    f32x4 acc = {0.f, 0.f, 0.f, 0.f};
    const char* hb = (const char*)hlds;
#pragma unroll
    for (int c = 0; c < 4; ++c) {
        f16x8 Af = *(const f16x8*)(hb + c * 1024 + lane * 16);
        f16x8 Bh = *(const f16x8*)(B2swz + (c * 4 + w) * 512 + lane * 8);
        acc = __builtin_amdgcn_mfma_f32_16x16x32_f16(Af, Bh, acc, 0, 0, 0);
    }
    const int colg = w * 16 + (lane & 15);
    const int rowb = blockIdx.x * 16 + (lane >> 4) * 4;
#pragma unroll
    for (int r = 0; r < 4; ++r) {
        int m = rowb + r;
        z0s[(size_t)m * C_OUT + colg] = f2h_bits(acc[r] * dinv[m]);  // f16
    }
}

// ---------------------------------------------------------------------------
// Fixed-slot CSR gather (layer 2, F=64), ONE-TEAM: 8 lanes/node, 32 nodes
// per block, packed col2 reads. z0s IS pre-scaled, f16. Output zbuf f16.
// ---------------------------------------------------------------------------
template<int F, bool RELU>
__global__ __launch_bounds__(256) void gather_kernel(
        const uint16_t* __restrict__ col2, const int* __restrict__ degc,
        const uint16_t* __restrict__ hs, const float* __restrict__ dinv,
        const float* __restrict__ bias, uint16_t* __restrict__ out) {
    constexpr int LPN = F / 8;          // 8 lanes per node
    constexpr int NPW = 64 / LPN;       // 8 nodes per wave
    const int lane = threadIdx.x & 63;
    const int sub  = lane / LPN;        // 0..7
    const int l    = lane % LPN;        // feature octet (0..7)
    const int node = blockIdx.x * (4 * NPW) + (threadIdx.x >> 6) * NPW + sub;
    if (node >= N_NODES) return;

    int dg = degc[node]; if (dg > SLOT) dg = SLOT;
    const uint4* hs4 = (const uint4*)hs;

    float a0[8], a1[8];
#pragma unroll
    for (int i = 0; i < 8; ++i) { a0[i] = 0.f; a1[i] = 0.f; }
    {
        uint4 self = hs4[(size_t)node * LPN + l];
        acc_h8(a0, self);
    }
    const uint32_t* cp = (const uint32_t*)col2;
    const int pbase = node * (SLOT / 2);
    const int sb    = sub * LPN;        // shfl base

    for (int c = 0; c * LPN < dg; ++c) {
        int cnt = dg - c * LPN; if (cnt > LPN) cnt = LPN;
        uint32_t cv = (2 * l < cnt) ? cp[pbase + c * (LPN / 2) + l] : 0u;
        int j = 0;
        for (; j + 8 <= cnt; j += 8) {
            uint32_t p0 = (uint32_t)__shfl((int)cv, sb + (j >> 1),     64);
            uint32_t p1 = (uint32_t)__shfl((int)cv, sb + (j >> 1) + 1, 64);
            uint32_t p2 = (uint32_t)__shfl((int)cv, sb + (j >> 1) + 2, 64);
            uint32_t p3 = (uint32_t)__shfl((int)cv, sb + (j >> 1) + 3, 64);
            int s0 = p0 & 0xffff, s1 = p0 >> 16;
            int s2 = p1 & 0xffff, s3 = p1 >> 16;
            int s4 = p2 & 0xffff, s5 = p2 >> 16;
            int s6 = p3 & 0xffff, s7 = p3 >> 16;
            uint4 v0 = hs4[(size_t)s0 * LPN + l];
            uint4 v1 = hs4[(size_t)s1 * LPN + l];
            uint4 v2 = hs4[(size_t)s2 * LPN + l];
            uint4 v3 = hs4[(size_t)s3 * LPN + l];
            uint4 v4 = hs4[(size_t)s4 * LPN + l];
            uint4 v5 = hs4[(size_t)s5 * LPN + l];
            uint4 v6 = hs4[(size_t)s6 * LPN + l];
            uint4 v7 = hs4[(size_t)s7 * LPN + l];
            acc_h8(a0, v0); acc_h8(a1, v1);
            acc_h8(a0, v2); acc_h8(a1, v3);
            acc_h8(a0, v4); acc_h8(a1, v5);
            acc_h8(a0, v6); acc_h8(a1, v7);
        }
        for (; j + 4 <= cnt; j += 4) {
            uint32_t p0 = (uint32_t)__shfl((int)cv, sb + (j >> 1),     64);
            uint32_t p1 = (uint32_t)__shfl((int)cv, sb + (j >> 1) + 1, 64);
            int s0 = p0 & 0xffff, s1 = p0 >> 16;
            int s2 = p1 & 0xffff, s3 = p1 >> 16;
            uint4 v0 = hs4[(size_t)s0 * LPN + l];
            uint4 v1 = hs4[(size_t)s1 * LPN + l];
            uint4 v2 = hs4[(size_t)s2 * LPN + l];
            uint4 v3 = hs4[(size_t)s3 * LPN + l];
            acc_h8(a0, v0); acc_h8(a1, v1);
            acc_h8(a0, v2); acc_h8(a1, v3);
        }
        for (; j < cnt; ++j) {
            uint32_t p = (uint32_t)__shfl((int)cv, sb + (j >> 1), 64);
            int s = (j & 1) ? (int)(p >> 16) : (int)(p & 0xffff);
            uint4 v = hs4[(size_t)s * LPN + l];
            acc_h8(a0, v);
        }
    }

    const float dn = dinv[node];
    float4 bb0 = ((const float4*)bias)[2 * l];
    float4 bb1 = ((const float4*)bias)[2 * l + 1];
    float o[8];
    o[0] = (a0[0] + a1[0]) * dn + bb0.x;
    o[1] = (a0[1] + a1[1]) * dn + bb0.y;
    o[2] = (a0[2] + a1[2]) * dn + bb0.z;
    o[3] = (a0[3] + a1[3]) * dn + bb0.w;
    o[4] = (a0[4] + a1[4]) * dn + bb1.x;
    o[5] = (a0[5] + a1[5]) * dn + bb1.y;
    o[6] = (a0[6] + a1[6]) * dn + bb1.z;
    o[7] = (a0[7] + a1[7]) * dn + bb1.w;
    if (RELU) {
#pragma unroll
        for (int i = 0; i < 8; ++i) o[i] = fmaxf(o[i], 0.f);
    }
    uint4 res = make_uint4(pack2h(o[0], o[1]), pack2h(o[2], o[3]),
                           pack2h(o[4], o[5]), pack2h(o[6], o[7]));
    ((uint4*)out)[(size_t)node * LPN + l] = res;
}

// ---------------------------------------------------------------------------
// logits: 8 lanes per edge, 2 edges per lane-group; z f16, v_dot2_f32_f16.
// ---------------------------------------------------------------------------
__global__ __launch_bounds__(256) void logits_kernel(
        const int* __restrict__ pos, const int* __restrict__ neg,
        const uint16_t* __restrict__ z, float* __restrict__ out) {
    const int t = threadIdx.x;
    const int l = t & 7;
    const int g = (blockIdx.x * 256 + t) >> 3;        // edge-pair id
    const int e0 = 2 * g;
    if (e0 >= 2 * E_PAIR) return;
    int s0, d0, s1, d1;
    if (e0 < E_PAIR) { s0 = pos[e0];          d0 = pos[E_PAIR + e0]; }
    else             { s0 = neg[e0 - E_PAIR]; d0 = neg[e0];          }
    int e1 = e0 + 1;
    if (e1 < E_PAIR) { s1 = pos[e1];          d1 = pos[E_PAIR + e1]; }
    else             { s1 = neg[e1 - E_PAIR]; d1 = neg[e1];          }
    const uint4* z4 = (const uint4*)z;
    uint4 ua0 = z4[(size_t)s0 * 8 + l];
    uint4 ub0 = z4[(size_t)d0 * 8 + l];
    uint4 ua1 = z4[(size_t)s1 * 8 + l];
    uint4 ub1 = z4[(size_t)d1 * 8 + l];
    float v0 = dot_h8(ua0, ub0);
    float v1 = dot_h8(ua1, ub1);
    v0 += __shfl_xor(v0, 1, 64); v1 += __shfl_xor(v1, 1, 64);
    v0 += __shfl_xor(v0, 2, 64); v1 += __shfl_xor(v1, 2, 64);
    v0 += __shfl_xor(v0, 4, 64); v1 += __shfl_xor(v1, 4, 64);
    if (l == 0) { out[e0] = v0; out[e1] = v1; }
}

// ---------------------------------------------------------------------------
extern "C" void kernel_launch(void* const* d_in, const int* in_sizes, int n_in,
                              void* d_out, int out_size, void* d_ws, size_t ws_size,
                              hipStream_t stream) {
    const float* x   = (const float*)d_in[0];
    const int*   ei  = (const int*)d_in[1];   // [2, E] : row0=src, row1=dst
    const int*   pos = (const int*)d_in[2];   // [2, E_PAIR]
    const int*   neg = (const int*)d_in[3];   // [2, E_PAIR]
    const float* W1  = (const float*)d_in[4];
    const float* b1  = (const float*)d_in[5];
    const float* W2  = (const float*)d_in[6];
    const float* b2  = (const float*)d_in[7];
    float* out = (float*)d_out;

    const int* src = ei;
    const int* dst = ei + E_EDGES;

    // Workspace layout (byte offsets, 256B-aligned):
    //   degc @0 (200704) | dinv @200704 (200704) | col2 @401408 (6.4MB u16)
    //   gcur @6801408 (1KB) | B1swz @6802432 (64KB used) | B2swz @6933504 (16KB used)
    //   h0u  @6966272 (12.8MB f16, UNSCALED) | z0s @32566272 (6.4MB f16)
    //   z    @38966272 (6.4MB f16) | ebuf @45366272 (3.7MB u32) -> ~49MB
    char* ws = (char*)d_ws;
    int*      degc  = (int*)ws;
    float*    dinv  = (float*)(ws + 200704);
    uint16_t* col2  = (uint16_t*)(ws + 401408);
    int*      gcur  = (int*)(ws + 6801408);
    uint16_t* B1swz = (uint16_t*)(ws + 6802432);
    uint16_t* B2swz = (uint16_t*)(ws + 6933504);
    uint16_t* h0u   = (uint16_t*)(ws + 6966272);
    uint16_t* z0s   = (uint16_t*)(ws + 32566272);
    uint16_t* zbuf  = (uint16_t*)(ws + 38966272);
    uint32_t* ebuf  = (uint32_t*)(ws + 45366272);

    // 0. zero per-bucket cursors (784 B memset, graph-capturable)
    hipMemsetAsync(gcur, 0, NBUCK * sizeof(int), stream);

    // 1. MERGED prep (W1/W2 -> f16 swizzle) + binA (LDS-binned edge pass)
    prep_binA_kernel<<<PREPB + BINAB, 256, 0, stream>>>(
        W1, W2, B1swz, B2swz, src, dst, gcur, ebuf);

    // 2. MERGED: binB LDS-staged (196 blocks) + gemm1-unscaled (782 blocks)
    build_gemm_kernel<<<NBUCK + GEMM1_BLOCKS, 256, 0, stream>>>(
        gcur, ebuf, col2, degc, dinv, x, B1swz, h0u);

    // 3. FUSED: h = relu((sum dinv[s]*h0u[s] + dinv[n]*h0u[n])*dinv[n] + b1);
    //    z0' = f16((h@W2)*dinv)  — one-team gather, packed col2 reads
    gather_gemm_kernel<<<N_NODES / 16, 256, 0, stream>>>(
        col2, degc, h0u, dinv, b1, B2swz, z0s);

    // 4. z = gather(z0') + b2 -> zbuf
    gather_kernel<C_OUT, false><<<(N_NODES + 31) / 32, 256, 0, stream>>>(
        col2, degc, z0s, dinv, b2, zbuf);

    // 5. logits over 400000 query edges (8 lanes/edge, 2 edges/group)
    logits_kernel<<<(E_PAIR * 8 + 255) / 256, 256, 0, stream>>>(pos, neg, zbuf, out);
}